// Round 13
// baseline (2551.424 us; speedup 1.0000x reference)
//
#include <hip/hip_runtime.h>
#include <stdint.h>

#define NB 128
#define NT 2048
#define NI 128
#define NH 1024
#define NO 128

typedef float f32x4 __attribute__((ext_vector_type(4)));

// ---------------------------------------------------------------------------
// W2P: pair-transpose W2 [O][H] -> W2P [H][64] of float2 {W2[j][k], W2[j+64][k]}
// ---------------------------------------------------------------------------
__global__ __launch_bounds__(256) void w2p_kernel(
    const float* __restrict__ W2, float2* __restrict__ W2P)
{
    const int idx = blockIdx.x * 256 + threadIdx.x;  // 0..65535
    const int k = idx >> 6;                          // 0..1023
    const int j = idx & 63;                          // 0..63
    W2P[idx] = make_float2(W2[(size_t)j * NH + k], W2[(size_t)(j + 64) * NH + k]);
}

#define LIFSTEP(TT, TACC)                                                 \
    {                                                                     \
        const float h1 = ((TACC + red[par][0][TT][lane]) +                \
                          (red[par][1][TT][lane] + red[par][2][TT][lane])) + \
                         bias;                                            \
        v = fmaf(h1 - v, 0.5f, v);                                        \
        const bool sp = (v >= 1.0f);                                      \
        v = sp ? 0.0f : v;                                                \
        const unsigned long long m = __ballot(sp);                        \
        if (lane == 0) s1w[(size_t)TT * NB * (NH / 64)] = (uint64_t)m;    \
    }

// ---------------------------------------------------------------------------
// Phase A5: fused GEMM1 + LIF1. Weights in LDS (4x t-amortized), x staged
// into LDS via double-buffered global_load_lds (async, vmcnt hidden under
// the chunk), consumed as wave-uniform broadcast ds_reads. NO SMEM drains.
// grid = 2048 (128 b x 16 hg of 64 h), block = 256 = 4 waves = 4 k-quarters
// (32 k) of the SAME 64 h (lane = h). LDS: wlds[64][33] f32x4 (padded, R12-
// verified conflict-free) + red (2-slot parity) + xlds[2][4][128] = 44 KB ->
// 3 blocks/CU. Per 4t per wave: 8 w-quads held in regs across 4 t's, 32
// broadcast x-quads, 128 FMA; 1 barrier; kq0 runs LIF+ballot for 4 t's.
// FMA order bit-identical to R12 (absmax 0.0).
// ---------------------------------------------------------------------------
__global__ __launch_bounds__(256, 3) void snn_phaseA5(
    const float* __restrict__ x, const float* __restrict__ W1,
    const float* __restrict__ b1, uint64_t* __restrict__ s1bits)
{
    const int b = blockIdx.x >> 4;      // 0..127
    const int hg = blockIdx.x & 15;     // 0..15
    const int wv = threadIdx.x >> 6;
    const int kq = __builtin_amdgcn_readfirstlane(wv);  // 0..3
    const int lane = threadIdx.x & 63;
    const int h = hg * 64 + lane;

    __shared__ f32x4 wlds[64][33];      // 33792 B, padded rows (R12-proven)
    __shared__ float red[2][3][4][64];  // 6144 B: [parity][kq-1][tt][h-lane]
    __shared__ float xlds[2][4][128];   // 4096 B: [buf][tt][k], linear order

    // Stage W1 tile [64 h][128 k]: 2048 16B quads, coalesced per row.
#pragma unroll
    for (int i = 0; i < 8; ++i) {
        const int c = threadIdx.x + i * 256;  // 0..2047
        const int r = c >> 5;                 // 0..63
        const int kc = c & 31;                // k-quad 0..31
        wlds[r][kc] = *reinterpret_cast<const f32x4*>(
            W1 + (size_t)(hg * 64 + r) * NI + kc * 4);
    }

    const float* __restrict__ xrow = x + (size_t)b * NT * NI;
    // Prologue: stage chunk 0 (t rows 0..3) into xlds[0]. Waves 0,1 each
    // stage 1024 B = 2 t-rows: per-lane global src, wave-uniform LDS dest.
    if (wv < 2) {
        __builtin_amdgcn_global_load_lds(xrow + wv * 256 + lane * 4,
                                         &xlds[0][wv * 2][0], 16, 0, 0);
    }
    asm volatile("s_waitcnt vmcnt(0)" ::: "memory");
    __syncthreads();  // covers wlds + x chunk 0

    const float bias = b1[h];
    const f32x4* __restrict__ wrow = &wlds[lane][0];
    const int wb = kq * 8;              // this wave's w-quad base (k = kq*32)

    uint64_t* s1w = s1bits + (size_t)b * (NH / 64) + hg;

    float v = 0.0f;
#pragma unroll 1
    for (int tc = 0; tc < NT; tc += 4) {
        const int par = (tc >> 2) & 1;
        // Issue next chunk's staging first; vmcnt lands before end barrier.
        if (wv < 2 && tc + 4 < NT) {
            __builtin_amdgcn_global_load_lds(
                xrow + (size_t)(tc + 4) * NI + wv * 256 + lane * 4,
                &xlds[par ^ 1][wv * 2][0], 16, 0, 0);
        }

        float t0 = 0.f, t1 = 0.f, t2 = 0.f, t3 = 0.f;
#pragma unroll
        for (int half = 0; half < 2; ++half) {
            const f32x4 w0 = wrow[wb + half * 4 + 0];
            const f32x4 w1 = wrow[wb + half * 4 + 1];
            const f32x4 w2 = wrow[wb + half * 4 + 2];
            const f32x4 w3 = wrow[wb + half * 4 + 3];
            const float* xk = &xlds[par][0][kq * 32 + half * 16];
            // per t: 16 FMAs, k ascending, single acc chain per t (R12 order)
#pragma unroll
            for (int tt = 0; tt < 4; ++tt) {
                const f32x4 xq0 = *reinterpret_cast<const f32x4*>(xk + tt * 128 + 0);
                const f32x4 xq1 = *reinterpret_cast<const f32x4*>(xk + tt * 128 + 4);
                const f32x4 xq2 = *reinterpret_cast<const f32x4*>(xk + tt * 128 + 8);
                const f32x4 xq3 = *reinterpret_cast<const f32x4*>(xk + tt * 128 + 12);
                float acc = (tt == 0) ? t0 : (tt == 1) ? t1 : (tt == 2) ? t2 : t3;
                acc = fmaf(w0.x, xq0[0], acc);
                acc = fmaf(w0.y, xq0[1], acc);
                acc = fmaf(w0.z, xq0[2], acc);
                acc = fmaf(w0.w, xq0[3], acc);
                acc = fmaf(w1.x, xq1[0], acc);
                acc = fmaf(w1.y, xq1[1], acc);
                acc = fmaf(w1.z, xq1[2], acc);
                acc = fmaf(w1.w, xq1[3], acc);
                acc = fmaf(w2.x, xq2[0], acc);
                acc = fmaf(w2.y, xq2[1], acc);
                acc = fmaf(w2.z, xq2[2], acc);
                acc = fmaf(w2.w, xq2[3], acc);
                acc = fmaf(w3.x, xq3[0], acc);
                acc = fmaf(w3.y, xq3[1], acc);
                acc = fmaf(w3.z, xq3[2], acc);
                acc = fmaf(w3.w, xq3[3], acc);
                if (tt == 0) t0 = acc; else if (tt == 1) t1 = acc;
                else if (tt == 2) t2 = acc; else t3 = acc;
            }
        }

        if (kq) {
            red[par][kq - 1][0][lane] = t0;
            red[par][kq - 1][1][lane] = t1;
            red[par][kq - 1][2][lane] = t2;
            red[par][kq - 1][3][lane] = t3;
        }
        asm volatile("s_waitcnt vmcnt(0)" ::: "memory");  // staging landed
        __syncthreads();
        if (!kq) {
            LIFSTEP(0, t0);
            LIFSTEP(1, t1);
            LIFSTEP(2, t2);
            LIFSTEP(3, t3);
        }
        s1w += (size_t)4 * NB * (NH / 64);
        // red[par]/xlds[par] re-written only after the next barrier: safe.
    }
}

// ---------------------------------------------------------------------------
// Phase B: sparse GEMM2 (proven). One wave per m = t*128+b row; per active
// spike one coalesced dwordx2 of W2P[k]. Sparse sum == dense sum exactly.
// ---------------------------------------------------------------------------
__global__ __launch_bounds__(256, 4) void snn_phaseB(
    const uint64_t* __restrict__ s1bits, const float2* __restrict__ W2P,
    float* __restrict__ h2)
{
    const int wv = threadIdx.x >> 6;
    const int lane = threadIdx.x & 63;
    const size_t m = (size_t)blockIdx.x * 4 + wv;  // 0..262143

    const uint64_t* __restrict__ sb = s1bits + m * (NH / 64);
    float a0 = 0.f, a1 = 0.f;

#pragma unroll 1
    for (int wd = 0; wd < NH / 64; ++wd) {
        const uint64_t m64 = sb[wd];
        const uint32_t mlo = (uint32_t)__builtin_amdgcn_readfirstlane((int)(uint32_t)m64);
        const uint32_t mhi = (uint32_t)__builtin_amdgcn_readfirstlane((int)(uint32_t)(m64 >> 32));
        uint64_t msk = ((uint64_t)mhi << 32) | mlo;
        while (msk) {
            const int i = __builtin_ctzll(msk);
            msk &= (msk - 1);
            const size_t k = ((size_t)wd << 6) + i;
            const float2 ww = W2P[k * 64 + lane];
            a0 += ww.x;
            a1 += ww.y;
        }
    }
    h2[m * NO + lane] = a0;
    h2[m * NO + 64 + lane] = a1;
}

// ---------------------------------------------------------------------------
// Phase D: LIF2 scan + decision-window count (proven).
// ---------------------------------------------------------------------------
__global__ __launch_bounds__(64) void snn_phaseD(
    const float* __restrict__ h2, const float* __restrict__ b2,
    float* __restrict__ out)
{
    const int idx = blockIdx.x * 64 + threadIdx.x;  // 0..16383
    const int b = idx >> 7;
    const int o = idx & 127;
    const float bias = b2[o];

    const float* __restrict__ p = h2 + (size_t)b * NO + o;
    float v = 0.f, c = 0.f;
#pragma unroll 16
    for (int t = 0; t < NT; ++t) {
        const float hh = p[(size_t)t * NB * NO] + bias;
        v = fmaf(hh - v, 0.5f, v);
        const bool s = (v >= 1.0f);
        v = s ? 0.f : v;
        if (t >= NT / 2) c += s ? 1.f : 0.f;
    }
    out[idx] = c;
}

extern "C" void kernel_launch(void* const* d_in, const int* in_sizes, int n_in,
                              void* d_out, int out_size, void* d_ws,
                              size_t ws_size, hipStream_t stream)
{
    const float* x  = (const float*)d_in[0];
    const float* W1 = (const float*)d_in[1];
    const float* b1 = (const float*)d_in[2];
    const float* W2 = (const float*)d_in[3];
    const float* b2 = (const float*)d_in[4];
    float* out = (float*)d_out;

    // ws layout: [s1bits 33.55 MB][W2P 0.52 MB][h2 134.2 MB]
    uint8_t* ws = (uint8_t*)d_ws;
    uint64_t* s1bits = (uint64_t*)ws;
    float2* W2P = (float2*)(ws + (size_t)NT * NB * (NH / 64) * 8);
    float* h2 = (float*)(ws + (size_t)NT * NB * (NH / 64) * 8 +
                         (size_t)NH * 64 * sizeof(float2));

    w2p_kernel<<<dim3((NH * 64) / 256), dim3(256), 0, stream>>>(W2, W2P);
    snn_phaseA5<<<dim3(NB * 16), dim3(256), 0, stream>>>(x, W1, b1, s1bits);
    snn_phaseB<<<dim3((NT * NB) / 4), dim3(256), 0, stream>>>(s1bits, W2P, h2);
    snn_phaseD<<<dim3(256), dim3(64), 0, stream>>>(h2, b2, out);
}

// Round 14
// 2082.483 us; speedup vs baseline: 1.2252x; 1.2252x over previous
//
#include <hip/hip_runtime.h>
#include <stdint.h>

#define NB 128
#define NT 2048
#define NI 128
#define NH 1024
#define NO 128

typedef float f32x4 __attribute__((ext_vector_type(4)));
typedef float f32x16 __attribute__((ext_vector_type(16)));

// ---------------------------------------------------------------------------
// W2P: pair-transpose W2 [O][H] -> W2P [H][64] of float2 {W2[j][k], W2[j+64][k]}
// ---------------------------------------------------------------------------
__global__ __launch_bounds__(256) void w2p_kernel(
    const float* __restrict__ W2, float2* __restrict__ W2P)
{
    const int idx = blockIdx.x * 256 + threadIdx.x;  // 0..65535
    const int k = idx >> 6;                          // 0..1023
    const int j = idx & 63;                          // 0..63
    W2P[idx] = make_float2(W2[(size_t)j * NH + k], W2[(size_t)(j + 64) * NH + k]);
}

// x 16-float chunk via SMEM scalar load (wave-uniform base, literal offset).
#define XL(DST, IMM)                                                      \
    asm volatile("s_load_dwordx16 %0, %1, " #IMM : "=s"(DST) : "s"(xb))

// 16 FMAs: one t's accumulator over this wave's 16 k (4 LDS weight quads),
// k ascending, single acc chain per t.
#define F16(ACC, XV)                                                      \
    do {                                                                  \
        ACC = fmaf(w0.x, (XV)[0],  ACC);                                  \
        ACC = fmaf(w0.y, (XV)[1],  ACC);                                  \
        ACC = fmaf(w0.z, (XV)[2],  ACC);                                  \
        ACC = fmaf(w0.w, (XV)[3],  ACC);                                  \
        ACC = fmaf(w1.x, (XV)[4],  ACC);                                  \
        ACC = fmaf(w1.y, (XV)[5],  ACC);                                  \
        ACC = fmaf(w1.z, (XV)[6],  ACC);                                  \
        ACC = fmaf(w1.w, (XV)[7],  ACC);                                  \
        ACC = fmaf(w2.x, (XV)[8],  ACC);                                  \
        ACC = fmaf(w2.y, (XV)[9],  ACC);                                  \
        ACC = fmaf(w2.z, (XV)[10], ACC);                                  \
        ACC = fmaf(w2.w, (XV)[11], ACC);                                  \
        ACC = fmaf(w3.x, (XV)[12], ACC);                                  \
        ACC = fmaf(w3.y, (XV)[13], ACC);                                  \
        ACC = fmaf(w3.z, (XV)[14], ACC);                                  \
        ACC = fmaf(w3.w, (XV)[15], ACC);                                  \
    } while (0)

#define LIFSTEP(TT, TACC)                                                 \
    {                                                                     \
        const float h1 =                                                  \
            (((TACC + red[par][0][TT][lane]) +                            \
              (red[par][1][TT][lane] + red[par][2][TT][lane])) +          \
             ((red[par][3][TT][lane] + red[par][4][TT][lane]) +           \
              (red[par][5][TT][lane] + red[par][6][TT][lane]))) +         \
            bias;                                                         \
        v = fmaf(h1 - v, 0.5f, v);                                        \
        const bool sp = (v >= 1.0f);                                      \
        v = sp ? 0.0f : v;                                                \
        const unsigned long long m = __ballot(sp);                        \
        if (lane == 0) s1w[(size_t)TT * NB * (NH / 64)] = (uint64_t)m;    \
    }

// ---------------------------------------------------------------------------
// Phase A6: fused GEMM1 + LIF1. R12's proven delivery (LDS weights + SMEM x)
// with 8-wave k-split: ONE SMEM drain per chunk and 6 waves/SIMD to hide it.
// grid = 2048 (128 b x 16 hg of 64 h), block = 512 = 8 waves = 8 k-eighths
// (16 k each) of the SAME 64 h (lane = h). LDS: wlds[64][33] f32x4 (padded,
// R12-verified conflict-free) + red[2][7][4][64] = 48.1 KB -> 3 blocks/CU
// = 6 waves/SIMD (vs R12's 4; drains of different blocks decorrelate).
// Per chunk (4t) per wave: 4x s_load_dwordx16 (one batch, ONE lgkmcnt(0)
// drain), 4 w-quads from LDS, 64 FMA; 1 barrier; kq0 wave (rotated per
// block) runs LIF + ballot + store for 4 t's.
// ---------------------------------------------------------------------------
__global__ __launch_bounds__(512, 6) void snn_phaseA6(
    const float* __restrict__ x, const float* __restrict__ W1,
    const float* __restrict__ b1, uint64_t* __restrict__ s1bits)
{
    const int b = blockIdx.x >> 4;      // 0..127
    const int hg = blockIdx.x & 15;     // 0..15
    const int wv = threadIdx.x >> 6;    // 0..7
    const int kq = __builtin_amdgcn_readfirstlane((wv + blockIdx.x) & 7);
    const int lane = threadIdx.x & 63;
    const int h = hg * 64 + lane;

    __shared__ f32x4 wlds[64][33];      // 33792 B, padded rows (R12-proven)
    __shared__ float red[2][7][4][64];  // 14336 B: [parity][kq-1][tt][h-lane]

    // Stage W1 tile [64 h][128 k]: 2048 16B quads, coalesced per row.
#pragma unroll
    for (int i = 0; i < 4; ++i) {
        const int c = threadIdx.x + i * 512;  // 0..2047
        const int r = c >> 5;                 // 0..63
        const int kc = c & 31;                // k-quad 0..31
        wlds[r][kc] = *reinterpret_cast<const f32x4*>(
            W1 + (size_t)(hg * 64 + r) * NI + kc * 4);
    }
    __syncthreads();

    const float bias = b1[h];
    const f32x4* __restrict__ wrow = &wlds[lane][0];
    const int wb = kq * 4;              // this wave's w-quad base (k = kq*16)

    const float* xb = x + (size_t)b * NT * NI + kq * 16;
    uint64_t* s1w = s1bits + (size_t)b * (NH / 64) + hg;

    float v = 0.0f;
#pragma unroll 1
    for (int tc = 0; tc < NT; tc += 4) {
        // x for 4 t's (this wave's 16 k): one batch, one drain.
        f32x16 xv0, xv1, xv2, xv3;
        XL(xv0, 0x0);
        XL(xv1, 0x200);
        XL(xv2, 0x400);
        XL(xv3, 0x600);
        asm volatile("s_waitcnt lgkmcnt(0)"
                     : "+s"(xv0), "+s"(xv1), "+s"(xv2), "+s"(xv3));
        __builtin_amdgcn_sched_barrier(0);

        const f32x4 w0 = wrow[wb + 0];
        const f32x4 w1 = wrow[wb + 1];
        const f32x4 w2 = wrow[wb + 2];
        const f32x4 w3 = wrow[wb + 3];

        float t0 = 0.f, t1 = 0.f, t2 = 0.f, t3 = 0.f;
        F16(t0, xv0);
        F16(t1, xv1);
        F16(t2, xv2);
        F16(t3, xv3);

        const int par = (tc >> 2) & 1;
        if (kq) {
            red[par][kq - 1][0][lane] = t0;
            red[par][kq - 1][1][lane] = t1;
            red[par][kq - 1][2][lane] = t2;
            red[par][kq - 1][3][lane] = t3;
        }
        __syncthreads();
        if (!kq) {
            LIFSTEP(0, t0);
            LIFSTEP(1, t1);
            LIFSTEP(2, t2);
            LIFSTEP(3, t3);
        }
        s1w += (size_t)4 * NB * (NH / 64);
        xb += 4 * NI;
        // red[par] slot re-written at tc+8, after barrier(tc+4): safe
        // (2-slot parity pattern proven R1/R5/R9/R12).
    }
}

// ---------------------------------------------------------------------------
// Phase B: sparse GEMM2 (proven). One wave per m = t*128+b row; per active
// spike one coalesced dwordx2 of W2P[k]. Sparse sum == dense sum exactly.
// ---------------------------------------------------------------------------
__global__ __launch_bounds__(256, 4) void snn_phaseB(
    const uint64_t* __restrict__ s1bits, const float2* __restrict__ W2P,
    float* __restrict__ h2)
{
    const int wv = threadIdx.x >> 6;
    const int lane = threadIdx.x & 63;
    const size_t m = (size_t)blockIdx.x * 4 + wv;  // 0..262143

    const uint64_t* __restrict__ sb = s1bits + m * (NH / 64);
    float a0 = 0.f, a1 = 0.f;

#pragma unroll 1
    for (int wd = 0; wd < NH / 64; ++wd) {
        const uint64_t m64 = sb[wd];
        const uint32_t mlo = (uint32_t)__builtin_amdgcn_readfirstlane((int)(uint32_t)m64);
        const uint32_t mhi = (uint32_t)__builtin_amdgcn_readfirstlane((int)(uint32_t)(m64 >> 32));
        uint64_t msk = ((uint64_t)mhi << 32) | mlo;
        while (msk) {
            const int i = __builtin_ctzll(msk);
            msk &= (msk - 1);
            const size_t k = ((size_t)wd << 6) + i;
            const float2 ww = W2P[k * 64 + lane];
            a0 += ww.x;
            a1 += ww.y;
        }
    }
    h2[m * NO + lane] = a0;
    h2[m * NO + 64 + lane] = a1;
}

// ---------------------------------------------------------------------------
// Phase D: LIF2 scan + decision-window count (proven).
// ---------------------------------------------------------------------------
__global__ __launch_bounds__(64) void snn_phaseD(
    const float* __restrict__ h2, const float* __restrict__ b2,
    float* __restrict__ out)
{
    const int idx = blockIdx.x * 64 + threadIdx.x;  // 0..16383
    const int b = idx >> 7;
    const int o = idx & 127;
    const float bias = b2[o];

    const float* __restrict__ p = h2 + (size_t)b * NO + o;
    float v = 0.f, c = 0.f;
#pragma unroll 16
    for (int t = 0; t < NT; ++t) {
        const float hh = p[(size_t)t * NB * NO] + bias;
        v = fmaf(hh - v, 0.5f, v);
        const bool s = (v >= 1.0f);
        v = s ? 0.f : v;
        if (t >= NT / 2) c += s ? 1.f : 0.f;
    }
    out[idx] = c;
}

extern "C" void kernel_launch(void* const* d_in, const int* in_sizes, int n_in,
                              void* d_out, int out_size, void* d_ws,
                              size_t ws_size, hipStream_t stream)
{
    const float* x  = (const float*)d_in[0];
    const float* W1 = (const float*)d_in[1];
    const float* b1 = (const float*)d_in[2];
    const float* W2 = (const float*)d_in[3];
    const float* b2 = (const float*)d_in[4];
    float* out = (float*)d_out;

    // ws layout: [s1bits 33.55 MB][W2P 0.52 MB][h2 134.2 MB]
    uint8_t* ws = (uint8_t*)d_ws;
    uint64_t* s1bits = (uint64_t*)ws;
    float2* W2P = (float2*)(ws + (size_t)NT * NB * (NH / 64) * 8);
    float* h2 = (float*)(ws + (size_t)NT * NB * (NH / 64) * 8 +
                         (size_t)NH * 64 * sizeof(float2));

    w2p_kernel<<<dim3((NH * 64) / 256), dim3(256), 0, stream>>>(W2, W2P);
    snn_phaseA6<<<dim3(NB * 16), dim3(512), 0, stream>>>(x, W1, b1, s1bits);
    snn_phaseB<<<dim3((NT * NB) / 4), dim3(256), 0, stream>>>(s1bits, W2P, h2);
    snn_phaseD<<<dim3(256), dim3(64), 0, stream>>>(h2, b2, out);
}